// Round 1
// baseline (834.441 us; speedup 1.0000x reference)
//
#include <hip/hip_runtime.h>
#include <stdint.h>
#include <math.h>

// ---------------------------------------------------------------------------
// SelfAttention: x[4,2048,1024] fp32, W_qkv[3072,1024], W_out[1024,1024]
// Strategy: bf16 MFMA everywhere, fp32 accuracy via hi/lo split-bf16 GEMMs
// (logical K'=3K with per-chunk physical remap: Ah*Bh + Al*Bh + Ah*Bl).
// ---------------------------------------------------------------------------

using short8 = __attribute__((ext_vector_type(8))) short;
using f32x4  = __attribute__((ext_vector_type(4))) float;

#define HID   1024
#define NHEAD 16
#define HDIM  64
#define NB    4
#define SEQ   2048
#define MROWS (NB*SEQ)   // 8192
#define KP    3072       // logical split-K
#define NKT   (KP/64)    // 48

typedef __attribute__((address_space(1))) const void* gas_t;
typedef __attribute__((address_space(3))) void*       las_t;

__device__ __forceinline__ uint16_t f2b(float f){
  uint32_t u = __float_as_uint(f);
  uint32_t r = (u + 0x7FFFu + ((u >> 16) & 1u)) >> 16;   // RNE
  return (uint16_t)r;
}
__device__ __forceinline__ float b2f(uint16_t h){
  return __uint_as_float(((uint32_t)h) << 16);
}

// fp32 [rows][1024] -> bf16 [rows][2048] = [hi | lo]; rows < nscale scaled 0.125
__global__ void split_hilo(const float* __restrict__ in, uint16_t* __restrict__ out,
                           int n, int nscale){
  int i = blockIdx.x * 256 + threadIdx.x;
  if (i >= n) return;
  int r = i >> 10, c = i & 1023;
  float v = in[i];
  if (r < nscale) v *= 0.125f;       // fold q-scale (exact, power of 2)
  uint16_t hi = f2b(v);
  uint16_t lo = f2b(v - b2f(hi));
  out[(size_t)r*2048 + c]        = hi;
  out[(size_t)r*2048 + 1024 + c] = lo;
}

// ---------------------------------------------------------------------------
// Split-K' GEMM: C[m][n] = sum_{k'=0..3071} A2[m][mapA(k')] * B2[n][mapB(k')]
//   A2 = [Ah|Al] (activations): mapA = k'<2048 ? k' : k'-2048   (Ah,Al,Ah)
//   B2 = [Bh|Bl] (weights):     mapB = k'<1024 ? k' : k'-1024   (Bh,Bh,Bl)
// => C = Ah*Bh + Al*Bh + Ah*Bl  (split-bf16 fp32 emulation)
// EPI=0: plain fp32 C.  EPI=1: qkv epilogue -> Qsplit/Ksplit/Vt buffers.
// ---------------------------------------------------------------------------
#define BM 128
#define BN 128
#define BKK 64

template<int EPI>
__global__ __launch_bounds__(256)
void gemm_split(const uint16_t* __restrict__ A, const uint16_t* __restrict__ B,
                float* __restrict__ C,
                uint16_t* __restrict__ qo, uint16_t* __restrict__ ko,
                uint16_t* __restrict__ vo,
                int M, int N)
{
  __shared__ __align__(16) uint16_t lA[BM*BKK];
  __shared__ __align__(16) uint16_t lB[BN*BKK];
  int t = threadIdx.x;
  int lane = t & 63, wid = t >> 6;
  int fq = lane >> 4, fr = lane & 15;
  int m0 = blockIdx.x * BM, n0 = blockIdx.y * BN;
  int wm = (wid >> 1) * 64, wn = (wid & 1) * 64;
  f32x4 acc[4][4] = {};

  for (int kt = 0; kt < NKT; ++kt){
    int kp = kt * BKK;
    int ka = (kp < 2048) ? kp : kp - 2048;
    int kb = (kp < 1024) ? kp : kp - 1024;
    const uint16_t* ga = A + (size_t)m0*2048 + ka;
    const uint16_t* gb = B + (size_t)n0*2048 + kb;
#pragma unroll
    for (int i = 0; i < 4; ++i){
      int e = (i*256 + t) * 8;
      int row = e >> 6, col = e & 63;
      __builtin_amdgcn_global_load_lds((gas_t)(ga + (size_t)row*2048 + col),
                                       (las_t)((char*)lA + (i*256 + wid*64)*16),
                                       16, 0, 0);
    }
#pragma unroll
    for (int i = 0; i < 4; ++i){
      int e = (i*256 + t) * 8;
      int row = e >> 6, col = e & 63;
      __builtin_amdgcn_global_load_lds((gas_t)(gb + (size_t)row*2048 + col),
                                       (las_t)((char*)lB + (i*256 + wid*64)*16),
                                       16, 0, 0);
    }
    __syncthreads();   // compiler emits vmcnt(0) drain before barrier
#pragma unroll
    for (int kc = 0; kc < 2; ++kc){
      short8 af[4], bfr[4];
#pragma unroll
      for (int mi = 0; mi < 4; ++mi)
        af[mi] = *(const short8*)&lA[(wm + mi*16 + fr)*BKK + kc*32 + fq*8];
#pragma unroll
      for (int ni = 0; ni < 4; ++ni)
        bfr[ni] = *(const short8*)&lB[(wn + ni*16 + fr)*BKK + kc*32 + fq*8];
#pragma unroll
      for (int mi = 0; mi < 4; ++mi)
#pragma unroll
        for (int ni = 0; ni < 4; ++ni)
          acc[mi][ni] = __builtin_amdgcn_mfma_f32_16x16x32_bf16(af[mi], bfr[ni],
                                                                acc[mi][ni], 0, 0, 0);
    }
    __syncthreads();
  }

  if (EPI == 0){
#pragma unroll
    for (int mi = 0; mi < 4; ++mi)
#pragma unroll
      for (int ni = 0; ni < 4; ++ni)
#pragma unroll
        for (int r = 0; r < 4; ++r){
          int m = m0 + wm + mi*16 + fq*4 + r;
          int n = n0 + wn + ni*16 + fr;
          C[(size_t)m*N + n] = acc[mi][ni][r];
        }
  } else {
    int cls = n0 >> 10;  // 0=q 1=k 2=v (128-wide tiles never straddle classes)
#pragma unroll
    for (int mi = 0; mi < 4; ++mi)
#pragma unroll
      for (int ni = 0; ni < 4; ++ni)
#pragma unroll
        for (int r = 0; r < 4; ++r){
          int m = m0 + wm + mi*16 + fq*4 + r;
          int n = n0 + wn + ni*16 + fr;
          float v = acc[mi][ni][r];
          int b = m >> 11, s = m & 2047;
          int nn = n & 1023;
          int h = nn >> 6, d = nn & 63;
          int bh = b*NHEAD + h;
          uint16_t hi = f2b(v);
          if (cls == 2){
            vo[((size_t)bh*HDIM + d)*SEQ + s] = hi;          // V transposed [bh][d][s]
          } else {
            uint16_t lo = f2b(v - b2f(hi));
            size_t base = ((size_t)bh*SEQ + s)*128;
            uint16_t* o = (cls == 0) ? qo : ko;
            o[base + d]      = hi;
            o[base + 64 + d] = lo;
          }
        }
  }
}

// ---------------------------------------------------------------------------
// Flash attention. Block = (bh, 64 q-rows), 4 waves x 16 rows each.
// Scores over logical K'=192: chunk c uses Q[qc[c]] x K[kc6[c]]:
//   qh*kh + qh*kh + ql*kh + ql*kh + qh*kl + qh*kl  (per 32-wide halves)
// Online softmax per q-row (rows live on (lane>>4)*4+reg; reduce over 16 cols
// via shfl_xor 1/2/4/8). P goes through per-wave LDS to become an A-fragment.
// ---------------------------------------------------------------------------
__global__ __launch_bounds__(256)
void attn_fused(const uint16_t* __restrict__ Qs, const uint16_t* __restrict__ Ks,
                const uint16_t* __restrict__ Vt, float* __restrict__ ctx)
{
  __shared__ __align__(16) uint16_t lK[64*128];    // 16 KB K-tile [64 keys][hi|lo]
  __shared__ __align__(16) uint16_t lP[4][16*64];  // 8 KB, per-wave P tile
  int t = threadIdx.x, lane = t & 63, wid = t >> 6;
  int fq = lane >> 4, fr = lane & 15;
  int qt = blockIdx.x, bh = blockIdx.y;
  const uint16_t* Qb = Qs + (size_t)bh*SEQ*128;
  const uint16_t* Kb = Ks + (size_t)bh*SEQ*128;
  const uint16_t* Vb = Vt + (size_t)bh*HDIM*SEQ;
  int qbase = qt*64 + wid*16;

  short8 qf[6];
#pragma unroll
  for (int c = 0; c < 6; ++c){
    const int qc[6] = {0,1,2,3,0,1};
    qf[c] = *(const short8*)&Qb[(size_t)(qbase + fr)*128 + qc[c]*32 + fq*8];
  }

  f32x4 accv[4] = {};
  float mrow[4] = {-1e30f,-1e30f,-1e30f,-1e30f};
  float lrow[4] = {0.f,0.f,0.f,0.f};

  for (int kt = 0; kt < SEQ/64; ++kt){
    const uint16_t* gk = Kb + (size_t)kt*64*128;   // contiguous 16 KB tile
#pragma unroll
    for (int i = 0; i < 4; ++i)
      __builtin_amdgcn_global_load_lds((gas_t)(gk + (i*256 + t)*8),
                                       (las_t)((char*)lK + (i*256 + wid*64)*16),
                                       16, 0, 0);
    __syncthreads();

    f32x4 sc[4] = {};
#pragma unroll
    for (int kcol = 0; kcol < 4; ++kcol){
#pragma unroll
      for (int c = 0; c < 6; ++c){
        const int qc[6]  = {0,1,2,3,0,1};
        const int kc6[6] = {0,1,0,1,2,3};
        short8 kf = *(const short8*)&lK[(kcol*16 + fr)*128 + kc6[c]*32 + fq*8];
        (void)qc;
        sc[kcol] = __builtin_amdgcn_mfma_f32_16x16x32_bf16(qf[c], kf, sc[kcol], 0, 0, 0);
      }
    }

    float scl[4];
#pragma unroll
    for (int r = 0; r < 4; ++r){
      float mx = fmaxf(fmaxf(sc[0][r], sc[1][r]), fmaxf(sc[2][r], sc[3][r]));
      mx = fmaxf(mx, __shfl_xor(mx, 1));
      mx = fmaxf(mx, __shfl_xor(mx, 2));
      mx = fmaxf(mx, __shfl_xor(mx, 4));
      mx = fmaxf(mx, __shfl_xor(mx, 8));
      float mnew = fmaxf(mrow[r], mx);
      scl[r] = __expf(mrow[r] - mnew);
      mrow[r] = mnew;
    }
    uint16_t* pw = &lP[wid][0];
    float psum[4] = {0.f,0.f,0.f,0.f};
#pragma unroll
    for (int kcol = 0; kcol < 4; ++kcol)
#pragma unroll
      for (int r = 0; r < 4; ++r){
        float p = __expf(sc[kcol][r] - mrow[r]);
        psum[r] += p;
        pw[(fq*4 + r)*64 + kcol*16 + fr] = f2b(p);
      }
#pragma unroll
    for (int r = 0; r < 4; ++r){
      float ps = psum[r];
      ps += __shfl_xor(ps, 1);
      ps += __shfl_xor(ps, 2);
      ps += __shfl_xor(ps, 4);
      ps += __shfl_xor(ps, 8);
      lrow[r] = lrow[r]*scl[r] + ps;
    }
#pragma unroll
    for (int df = 0; df < 4; ++df)
#pragma unroll
      for (int r = 0; r < 4; ++r)
        accv[df][r] *= scl[r];

    asm volatile("s_waitcnt lgkmcnt(0)" ::: "memory");  // P writes -> P reads (wave-local)

#pragma unroll
    for (int kc = 0; kc < 2; ++kc){
      short8 pf = *(const short8*)&pw[fr*64 + kc*32 + fq*8];
#pragma unroll
      for (int df = 0; df < 4; ++df){
        short8 vf = *(const short8*)&Vb[(size_t)(df*16 + fr)*SEQ + kt*64 + kc*32 + fq*8];
        accv[df] = __builtin_amdgcn_mfma_f32_16x16x32_bf16(pf, vf, accv[df], 0, 0, 0);
      }
    }
    __syncthreads();   // protect lK before next stage
  }

  int b = bh >> 4, h = bh & 15;
#pragma unroll
  for (int df = 0; df < 4; ++df)
#pragma unroll
    for (int r = 0; r < 4; ++r){
      int q = qbase + fq*4 + r;
      int col = h*64 + df*16 + fr;
      ctx[((size_t)(b*SEQ + q))*HID + col] = accv[df][r] / lrow[r];
    }
}

// ---------------------------------------------------------------------------
extern "C" void kernel_launch(void* const* d_in, const int* in_sizes, int n_in,
                              void* d_out, int out_size, void* d_ws, size_t ws_size,
                              hipStream_t stream)
{
  const float* x  = (const float*)d_in[0];
  const float* Wq = (const float*)d_in[1];
  const float* Wo = (const float*)d_in[2];
  float* out = (float*)d_out;
  char* ws = (char*)d_ws;

  // workspace layout (total 130,023,424 B) with lifetime-based reuse
  uint16_t* XS = (uint16_t*)(ws);                 // [8192][2048] x split     33.55 MB
  uint16_t* WQ = (uint16_t*)(ws + 33554432);      // [3072][2048] Wqkv split  12.58 MB
  uint16_t* QS = (uint16_t*)(ws + 46137344);      // [bh][s][128] q hi|lo     33.55 MB
  uint16_t* KS = (uint16_t*)(ws + 79691776);      // [bh][s][128] k hi|lo     33.55 MB
  uint16_t* VT = (uint16_t*)(ws + 113246208);     // [bh][d][s]   v bf16      16.78 MB
  float*    CX = (float*)(ws);                    // ctx fp32 (reuses XS)
  uint16_t* CS = (uint16_t*)(ws + 46137344);      // ctx split (reuses QS)
  uint16_t* WS = (uint16_t*)(ws + 33554432);      // Wout split (reuses WQ)

  split_hilo<<<(MROWS*HID)/256, 256, 0, stream>>>(x, XS, MROWS*HID, 0);
  split_hilo<<<(3*HID*HID)/256, 256, 0, stream>>>(Wq, WQ, 3*HID*HID, HID);

  dim3 g1(MROWS/128, (3*HID)/128);
  gemm_split<1><<<g1, 256, 0, stream>>>(XS, WQ, nullptr, QS, KS, VT, MROWS, 3*HID);

  dim3 g2(SEQ/64, NB*NHEAD);
  attn_fused<<<g2, 256, 0, stream>>>(QS, KS, VT, CX);

  split_hilo<<<(MROWS*HID)/256, 256, 0, stream>>>(CX, CS, MROWS*HID, 0);
  split_hilo<<<(HID*HID)/256, 256, 0, stream>>>(Wo, WS, HID*HID, 0);

  dim3 g3(MROWS/128, HID/128);
  gemm_split<0><<<g3, 256, 0, stream>>>(CS, WS, out, nullptr, nullptr, nullptr, MROWS, HID);
}

// Round 2
// 575.358 us; speedup vs baseline: 1.4503x; 1.4503x over previous
//
#include <hip/hip_runtime.h>
#include <hip/hip_bf16.h>
#include <stdint.h>
#include <math.h>

// ---------------------------------------------------------------------------
// SelfAttention: x[4,2048,1024] fp32, W_qkv[3072,1024], W_out[1024,1024]
// bf16 MFMA everywhere; fp32 accuracy via hi/lo split-bf16 GEMMs.
// R2: attn rework — XOR-swizzled lK/lP (kills 16-way bank conflict),
//     32 q-rows/wave, double-buffered K tile (1 barrier/iter),
//     XCD-bijective block swizzle, setprio around MFMA clusters.
// ---------------------------------------------------------------------------

using short8 = __attribute__((ext_vector_type(8))) short;
using f32x4  = __attribute__((ext_vector_type(4))) float;

#define HID   1024
#define NHEAD 16
#define HDIM  64
#define NB    4
#define SEQ   2048
#define MROWS (NB*SEQ)   // 8192
#define KP    3072       // logical split-K
#define NKT   (KP/64)    // 48

typedef __attribute__((address_space(1))) const void* gas_t;
typedef __attribute__((address_space(3))) void*       las_t;

__device__ __forceinline__ uint16_t f2b(float f){
  uint32_t u = __float_as_uint(f);
  uint32_t r = (u + 0x7FFFu + ((u >> 16) & 1u)) >> 16;   // RNE
  return (uint16_t)r;
}
__device__ __forceinline__ float b2f(uint16_t h){
  return __uint_as_float(((uint32_t)h) << 16);
}

// fp32 [rows][1024] -> bf16 [rows][2048] = [hi | lo]; rows < nscale scaled 0.125
__global__ void split_hilo(const float* __restrict__ in, uint16_t* __restrict__ out,
                           int n, int nscale){
  int i = blockIdx.x * 256 + threadIdx.x;
  if (i >= n) return;
  int r = i >> 10, c = i & 1023;
  float v = in[i];
  if (r < nscale) v *= 0.125f;       // fold q-scale (exact, power of 2)
  uint16_t hi = f2b(v);
  uint16_t lo = f2b(v - b2f(hi));
  out[(size_t)r*2048 + c]        = hi;
  out[(size_t)r*2048 + 1024 + c] = lo;
}

// ---------------------------------------------------------------------------
// Split-K' GEMM (unchanged from R1; working, ~37% MfmaUtil expected)
// ---------------------------------------------------------------------------
#define BM 128
#define BN 128
#define BKK 64

template<int EPI>
__global__ __launch_bounds__(256)
void gemm_split(const uint16_t* __restrict__ A, const uint16_t* __restrict__ B,
                float* __restrict__ C,
                uint16_t* __restrict__ qo, uint16_t* __restrict__ ko,
                uint16_t* __restrict__ vo,
                int M, int N)
{
  __shared__ __align__(16) uint16_t lA[BM*BKK];
  __shared__ __align__(16) uint16_t lB[BN*BKK];
  int t = threadIdx.x;
  int lane = t & 63, wid = t >> 6;
  int fq = lane >> 4, fr = lane & 15;
  int m0 = blockIdx.x * BM, n0 = blockIdx.y * BN;
  int wm = (wid >> 1) * 64, wn = (wid & 1) * 64;
  f32x4 acc[4][4] = {};

  for (int kt = 0; kt < NKT; ++kt){
    int kp = kt * BKK;
    int ka = (kp < 2048) ? kp : kp - 2048;
    int kb = (kp < 1024) ? kp : kp - 1024;
    const uint16_t* ga = A + (size_t)m0*2048 + ka;
    const uint16_t* gb = B + (size_t)n0*2048 + kb;
#pragma unroll
    for (int i = 0; i < 4; ++i){
      int e = (i*256 + t) * 8;
      int row = e >> 6, col = e & 63;
      __builtin_amdgcn_global_load_lds((gas_t)(ga + (size_t)row*2048 + col),
                                       (las_t)((char*)lA + (i*256 + wid*64)*16),
                                       16, 0, 0);
    }
#pragma unroll
    for (int i = 0; i < 4; ++i){
      int e = (i*256 + t) * 8;
      int row = e >> 6, col = e & 63;
      __builtin_amdgcn_global_load_lds((gas_t)(gb + (size_t)row*2048 + col),
                                       (las_t)((char*)lB + (i*256 + wid*64)*16),
                                       16, 0, 0);
    }
    __syncthreads();
#pragma unroll
    for (int kc = 0; kc < 2; ++kc){
      short8 af[4], bfr[4];
#pragma unroll
      for (int mi = 0; mi < 4; ++mi)
        af[mi] = *(const short8*)&lA[(wm + mi*16 + fr)*BKK + kc*32 + fq*8];
#pragma unroll
      for (int ni = 0; ni < 4; ++ni)
        bfr[ni] = *(const short8*)&lB[(wn + ni*16 + fr)*BKK + kc*32 + fq*8];
#pragma unroll
      for (int mi = 0; mi < 4; ++mi)
#pragma unroll
        for (int ni = 0; ni < 4; ++ni)
          acc[mi][ni] = __builtin_amdgcn_mfma_f32_16x16x32_bf16(af[mi], bfr[ni],
                                                                acc[mi][ni], 0, 0, 0);
    }
    __syncthreads();
  }

  if (EPI == 0){
#pragma unroll
    for (int mi = 0; mi < 4; ++mi)
#pragma unroll
      for (int ni = 0; ni < 4; ++ni)
#pragma unroll
        for (int r = 0; r < 4; ++r){
          int m = m0 + wm + mi*16 + fq*4 + r;
          int n = n0 + wn + ni*16 + fr;
          C[(size_t)m*N + n] = acc[mi][ni][r];
        }
  } else {
    int cls = n0 >> 10;  // 0=q 1=k 2=v
#pragma unroll
    for (int mi = 0; mi < 4; ++mi)
#pragma unroll
      for (int ni = 0; ni < 4; ++ni)
#pragma unroll
        for (int r = 0; r < 4; ++r){
          int m = m0 + wm + mi*16 + fq*4 + r;
          int n = n0 + wn + ni*16 + fr;
          float v = acc[mi][ni][r];
          int b = m >> 11, s = m & 2047;
          int nn = n & 1023;
          int h = nn >> 6, d = nn & 63;
          int bh = b*NHEAD + h;
          uint16_t hi = f2b(v);
          if (cls == 2){
            vo[((size_t)bh*HDIM + d)*SEQ + s] = hi;          // V transposed [bh][d][s]
          } else {
            uint16_t lo = f2b(v - b2f(hi));
            size_t base = ((size_t)bh*SEQ + s)*128;
            uint16_t* o = (cls == 0) ? qo : ko;
            o[base + d]      = hi;
            o[base + 64 + d] = lo;
          }
        }
  }
}

// ---------------------------------------------------------------------------
// Flash attention R2.
// Block = (bh, 128 q-rows), 4 waves x 32 rows (2 row-groups of 16).
// lK: [64 keys][128 cols bf16] = 256 B rows, XOR-swizzled byte^=((row&7)<<4);
//     staged via global_load_lds with inverse-swizzled GLOBAL source (linear
//     LDS dest), double-buffered, single barrier per K-tile.
// lP: per-wave [32][64] bf16, 128 B rows, same XOR swizzle.
// ---------------------------------------------------------------------------
#define KVB 64
#define NKTILES (SEQ/KVB)   // 32

__device__ __forceinline__ void stage_k(const uint16_t* __restrict__ Kb, int kt,
                                        char* dst, int t, int wid){
  const char* gk = (const char*)(Kb + (size_t)kt*KVB*128);
#pragma unroll
  for (int i = 0; i < 4; ++i){
    int tl = i*256 + t;
    int row = tl >> 4;              // 256B-row index of this thread's 16B slot
    int o   = tl*16;
    __builtin_amdgcn_global_load_lds((gas_t)(gk + (o ^ ((row&7)<<4))),
                                     (las_t)(dst + (i*256 + wid*64)*16),
                                     16, 0, 0);
  }
}

__global__ __launch_bounds__(256)
void attn_fused(const uint16_t* __restrict__ Qs, const uint16_t* __restrict__ Ks,
                const uint16_t* __restrict__ Vt, float* __restrict__ ctx)
{
  __shared__ __align__(16) char lK[2][KVB*256];   // 2 x 16 KB, swizzled
  __shared__ __align__(16) char lP[4][4096];      // per-wave 32x64 bf16, swizzled
  int t = threadIdx.x, lane = t & 63, wid = t >> 6;
  int fq = lane >> 4, fr = lane & 15;

  // XCD-bijective swizzle: 1024 blocks, 8 XCDs, 128 per XCD -> same-bh
  // blocks land on one XCD (K/V L2 locality).
  int orig = blockIdx.x;
  int wg = (orig & 7) * 128 + (orig >> 3);
  int bh = wg >> 4, qt = wg & 15;

  const uint16_t* Qb = Qs + (size_t)bh*SEQ*128;
  const uint16_t* Kb = Ks + (size_t)bh*SEQ*128;
  const uint16_t* Vb = Vt + (size_t)bh*HDIM*SEQ;
  int qbase = qt*128 + wid*32;

  const int qc[6]  = {0,1,2,3,0,1};
  const int kc6[6] = {0,1,0,1,2,3};

  short8 qf[2][6];
#pragma unroll
  for (int rg = 0; rg < 2; ++rg)
#pragma unroll
    for (int c = 0; c < 6; ++c)
      qf[rg][c] = *(const short8*)&Qb[(size_t)(qbase + rg*16 + fr)*128 + qc[c]*32 + fq*8];

  f32x4 accv[2][4] = {};
  float mrow[2][4], lrow[2][4];
#pragma unroll
  for (int rg = 0; rg < 2; ++rg)
#pragma unroll
    for (int r = 0; r < 4; ++r){ mrow[rg][r] = -1e30f; lrow[rg][r] = 0.f; }

  stage_k(Kb, 0, lK[0], t, wid);
  __syncthreads();
  int cur = 0;

  for (int kt = 0; kt < NKTILES; ++kt){
    if (kt + 1 < NKTILES) stage_k(Kb, kt + 1, lK[cur ^ 1], t, wid);

    const char* kb = lK[cur];
    f32x4 sc[2][4] = {};
    __builtin_amdgcn_s_setprio(1);
#pragma unroll
    for (int kcol = 0; kcol < 4; ++kcol){
      int r = kcol*16 + fr;
      int rx = (r & 7) << 4;
#pragma unroll
      for (int c = 0; c < 6; ++c){
        int cb = kc6[c]*64 + fq*16;
        short8 kf = *(const short8*)(kb + r*256 + (cb ^ rx));
        sc[0][kcol] = __builtin_amdgcn_mfma_f32_16x16x32_bf16(qf[0][c], kf, sc[0][kcol], 0, 0, 0);
        sc[1][kcol] = __builtin_amdgcn_mfma_f32_16x16x32_bf16(qf[1][c], kf, sc[1][kcol], 0, 0, 0);
      }
    }
    __builtin_amdgcn_s_setprio(0);

    char* pw = lP[wid];
    float scl[2][4];
#pragma unroll
    for (int rg = 0; rg < 2; ++rg)
#pragma unroll
      for (int r = 0; r < 4; ++r){
        float mx = fmaxf(fmaxf(sc[rg][0][r], sc[rg][1][r]),
                         fmaxf(sc[rg][2][r], sc[rg][3][r]));
        mx = fmaxf(mx, __shfl_xor(mx, 1));
        mx = fmaxf(mx, __shfl_xor(mx, 2));
        mx = fmaxf(mx, __shfl_xor(mx, 4));
        mx = fmaxf(mx, __shfl_xor(mx, 8));
        float mnew = fmaxf(mrow[rg][r], mx);
        scl[rg][r] = __expf(mrow[rg][r] - mnew);
        mrow[rg][r] = mnew;
      }

    float psum[2][4] = {};
#pragma unroll
    for (int rg = 0; rg < 2; ++rg)
#pragma unroll
      for (int kcol = 0; kcol < 4; ++kcol)
#pragma unroll
        for (int r = 0; r < 4; ++r){
          float p = __expf(sc[rg][kcol][r] - mrow[rg][r]);
          psum[rg][r] += p;
          int row = rg*16 + fq*4 + r;
          int cbyte = kcol*32 + fr*2;
          *(uint16_t*)(pw + row*128 + (cbyte ^ ((row&7)<<4))) = f2b(p);
        }

#pragma unroll
    for (int rg = 0; rg < 2; ++rg)
#pragma unroll
      for (int r = 0; r < 4; ++r){
        float ps = psum[rg][r];
        ps += __shfl_xor(ps, 1);
        ps += __shfl_xor(ps, 2);
        ps += __shfl_xor(ps, 4);
        ps += __shfl_xor(ps, 8);
        lrow[rg][r] = lrow[rg][r]*scl[rg][r] + ps;
      }
#pragma unroll
    for (int rg = 0; rg < 2; ++rg)
#pragma unroll
      for (int df = 0; df < 4; ++df)
#pragma unroll
        for (int r = 0; r < 4; ++r)
          accv[rg][df][r] *= scl[rg][r];

    asm volatile("s_waitcnt lgkmcnt(0)" ::: "memory");   // P writes -> P reads
    __builtin_amdgcn_sched_barrier(0);

    __builtin_amdgcn_s_setprio(1);
#pragma unroll
    for (int kc = 0; kc < 2; ++kc){
      short8 pf[2];
#pragma unroll
      for (int rg = 0; rg < 2; ++rg){
        int row = rg*16 + fr;
        int cbyte = kc*64 + fq*16;
        pf[rg] = *(const short8*)(pw + row*128 + (cbyte ^ ((row&7)<<4)));
      }
#pragma unroll
      for (int df = 0; df < 4; ++df){
        short8 vf = *(const short8*)&Vb[(size_t)(df*16 + fr)*SEQ + kt*KVB + kc*32 + fq*8];
        accv[0][df] = __builtin_amdgcn_mfma_f32_16x16x32_bf16(pf[0], vf, accv[0][df], 0, 0, 0);
        accv[1][df] = __builtin_amdgcn_mfma_f32_16x16x32_bf16(pf[1], vf, accv[1][df], 0, 0, 0);
      }
    }
    __builtin_amdgcn_s_setprio(0);

    __syncthreads();   // all waves done reading lK[cur]; staged tile landed
    cur ^= 1;
  }

  int b = bh >> 4, h = bh & 15;
#pragma unroll
  for (int rg = 0; rg < 2; ++rg)
#pragma unroll
    for (int df = 0; df < 4; ++df)
#pragma unroll
      for (int r = 0; r < 4; ++r){
        int q = qbase + rg*16 + fq*4 + r;
        int col = h*64 + df*16 + fr;
        ctx[((size_t)(b*SEQ + q))*HID + col] = accv[rg][df][r] / lrow[rg][r];
      }
}

// ---------------------------------------------------------------------------
extern "C" void kernel_launch(void* const* d_in, const int* in_sizes, int n_in,
                              void* d_out, int out_size, void* d_ws, size_t ws_size,
                              hipStream_t stream)
{
  const float* x  = (const float*)d_in[0];
  const float* Wq = (const float*)d_in[1];
  const float* Wo = (const float*)d_in[2];
  float* out = (float*)d_out;
  char* ws = (char*)d_ws;

  uint16_t* XS = (uint16_t*)(ws);                 // [8192][2048] x split     33.55 MB
  uint16_t* WQ = (uint16_t*)(ws + 33554432);      // [3072][2048] Wqkv split  12.58 MB
  uint16_t* QS = (uint16_t*)(ws + 46137344);      // [bh][s][128] q hi|lo     33.55 MB
  uint16_t* KS = (uint16_t*)(ws + 79691776);      // [bh][s][128] k hi|lo     33.55 MB
  uint16_t* VT = (uint16_t*)(ws + 113246208);     // [bh][d][s]   v bf16      16.78 MB
  float*    CX = (float*)(ws);                    // ctx fp32 (reuses XS)
  uint16_t* CS = (uint16_t*)(ws + 46137344);      // ctx split (reuses QS)
  uint16_t* WS = (uint16_t*)(ws + 33554432);      // Wout split (reuses WQ)

  split_hilo<<<(MROWS*HID)/256, 256, 0, stream>>>(x, XS, MROWS*HID, 0);
  split_hilo<<<(3*HID*HID)/256, 256, 0, stream>>>(Wq, WQ, 3*HID*HID, HID);

  dim3 g1(MROWS/128, (3*HID)/128);
  gemm_split<1><<<g1, 256, 0, stream>>>(XS, WQ, nullptr, QS, KS, VT, MROWS, 3*HID);

  attn_fused<<<dim3(1024), 256, 0, stream>>>(QS, KS, VT, CX);

  split_hilo<<<(MROWS*HID)/256, 256, 0, stream>>>(CX, CS, MROWS*HID, 0);
  split_hilo<<<(HID*HID)/256, 256, 0, stream>>>(Wo, WS, HID*HID, 0);

  dim3 g3(MROWS/128, HID/128);
  gemm_split<0><<<g3, 256, 0, stream>>>(CS, WS, out, nullptr, nullptr, nullptr, MROWS, HID);
}

// Round 3
// 456.509 us; speedup vs baseline: 1.8279x; 1.2603x over previous
//
#include <hip/hip_runtime.h>
#include <hip/hip_bf16.h>
#include <stdint.h>
#include <math.h>

// ---------------------------------------------------------------------------
// SelfAttention: x[4,2048,1024] fp32, W_qkv[3072,1024], W_out[1024,1024]
// bf16 MFMA everywhere; fp32 accuracy via hi/lo split-bf16 GEMMs.
// R3: attn rewritten on 32x32x16 MFMA with swapped operands (T12 structure):
//     QK^T = mfma(K,Q) -> lane-local q-row softmax (in-lane tree + 1 shfl),
//     P->frag via v_cvt_pk_bf16_f32 + v_permlane32_swap_b32 (no P LDS),
//     PV = mfma(Vt,P) -> lane-local output + denom, exp2 domain (log2e folded
//     into q-scale), defer-max THR=8.
// ---------------------------------------------------------------------------

using short8 = __attribute__((ext_vector_type(8))) short;
using f32x4  = __attribute__((ext_vector_type(4))) float;
using f32x16 = __attribute__((ext_vector_type(16))) float;
using u32x4  = __attribute__((ext_vector_type(4))) unsigned int;

#define HID   1024
#define NHEAD 16
#define HDIM  64
#define NB    4
#define SEQ   2048
#define MROWS (NB*SEQ)   // 8192
#define KP    3072       // logical split-K
#define NKT   (KP/64)    // 48

typedef __attribute__((address_space(1))) const void* gas_t;
typedef __attribute__((address_space(3))) void*       las_t;

__device__ __forceinline__ uint16_t f2b(float f){
  uint32_t u = __float_as_uint(f);
  uint32_t r = (u + 0x7FFFu + ((u >> 16) & 1u)) >> 16;   // RNE
  return (uint16_t)r;
}
__device__ __forceinline__ float b2f(uint16_t h){
  return __uint_as_float(((uint32_t)h) << 16);
}

// fp32 [rows][1024] -> bf16 [rows][2048] = [hi | lo]; rows < nscale scaled by qs
__global__ void split_hilo(const float* __restrict__ in, uint16_t* __restrict__ out,
                           int n, int nscale, float qs){
  int i = blockIdx.x * 256 + threadIdx.x;
  if (i >= n) return;
  int r = i >> 10, c = i & 1023;
  float v = in[i];
  if (r < nscale) v *= qs;           // q-scale (incl. log2e for exp2-domain)
  uint16_t hi = f2b(v);
  uint16_t lo = f2b(v - b2f(hi));
  out[(size_t)r*2048 + c]        = hi;
  out[(size_t)r*2048 + 1024 + c] = lo;
}

// ---------------------------------------------------------------------------
// Split-K' GEMM (frozen from R1/R2)
// ---------------------------------------------------------------------------
#define BM 128
#define BN 128
#define BKK 64

template<int EPI>
__global__ __launch_bounds__(256)
void gemm_split(const uint16_t* __restrict__ A, const uint16_t* __restrict__ B,
                float* __restrict__ C,
                uint16_t* __restrict__ qo, uint16_t* __restrict__ ko,
                uint16_t* __restrict__ vo,
                int M, int N)
{
  __shared__ __align__(16) uint16_t lA[BM*BKK];
  __shared__ __align__(16) uint16_t lB[BN*BKK];
  int t = threadIdx.x;
  int lane = t & 63, wid = t >> 6;
  int fq = lane >> 4, fr = lane & 15;
  int m0 = blockIdx.x * BM, n0 = blockIdx.y * BN;
  int wm = (wid >> 1) * 64, wn = (wid & 1) * 64;
  f32x4 acc[4][4] = {};

  for (int kt = 0; kt < NKT; ++kt){
    int kp = kt * BKK;
    int ka = (kp < 2048) ? kp : kp - 2048;
    int kb = (kp < 1024) ? kp : kp - 1024;
    const uint16_t* ga = A + (size_t)m0*2048 + ka;
    const uint16_t* gb = B + (size_t)n0*2048 + kb;
#pragma unroll
    for (int i = 0; i < 4; ++i){
      int e = (i*256 + t) * 8;
      int row = e >> 6, col = e & 63;
      __builtin_amdgcn_global_load_lds((gas_t)(ga + (size_t)row*2048 + col),
                                       (las_t)((char*)lA + (i*256 + wid*64)*16),
                                       16, 0, 0);
    }
#pragma unroll
    for (int i = 0; i < 4; ++i){
      int e = (i*256 + t) * 8;
      int row = e >> 6, col = e & 63;
      __builtin_amdgcn_global_load_lds((gas_t)(gb + (size_t)row*2048 + col),
                                       (las_t)((char*)lB + (i*256 + wid*64)*16),
                                       16, 0, 0);
    }
    __syncthreads();
#pragma unroll
    for (int kc = 0; kc < 2; ++kc){
      short8 af[4], bfr[4];
#pragma unroll
      for (int mi = 0; mi < 4; ++mi)
        af[mi] = *(const short8*)&lA[(wm + mi*16 + fr)*BKK + kc*32 + fq*8];
#pragma unroll
      for (int ni = 0; ni < 4; ++ni)
        bfr[ni] = *(const short8*)&lB[(wn + ni*16 + fr)*BKK + kc*32 + fq*8];
#pragma unroll
      for (int mi = 0; mi < 4; ++mi)
#pragma unroll
        for (int ni = 0; ni < 4; ++ni)
          acc[mi][ni] = __builtin_amdgcn_mfma_f32_16x16x32_bf16(af[mi], bfr[ni],
                                                                acc[mi][ni], 0, 0, 0);
    }
    __syncthreads();
  }

  if (EPI == 0){
#pragma unroll
    for (int mi = 0; mi < 4; ++mi)
#pragma unroll
      for (int ni = 0; ni < 4; ++ni)
#pragma unroll
        for (int r = 0; r < 4; ++r){
          int m = m0 + wm + mi*16 + fq*4 + r;
          int n = n0 + wn + ni*16 + fr;
          C[(size_t)m*N + n] = acc[mi][ni][r];
        }
  } else {
    int cls = n0 >> 10;  // 0=q 1=k 2=v
#pragma unroll
    for (int mi = 0; mi < 4; ++mi)
#pragma unroll
      for (int ni = 0; ni < 4; ++ni)
#pragma unroll
        for (int r = 0; r < 4; ++r){
          int m = m0 + wm + mi*16 + fq*4 + r;
          int n = n0 + wn + ni*16 + fr;
          float v = acc[mi][ni][r];
          int b = m >> 11, s = m & 2047;
          int nn = n & 1023;
          int h = nn >> 6, d = nn & 63;
          int bh = b*NHEAD + h;
          uint16_t hi = f2b(v);
          if (cls == 2){
            vo[((size_t)bh*HDIM + d)*SEQ + s] = hi;          // V transposed [bh][d][s]
          } else {
            uint16_t lo = f2b(v - b2f(hi));
            size_t base = ((size_t)bh*SEQ + s)*128;
            uint16_t* o = (cls == 0) ? qo : ko;
            o[base + d]      = hi;
            o[base + 64 + d] = lo;
          }
        }
  }
}

// ---------------------------------------------------------------------------
// Flash attention R3 (swapped-operand 32x32).
// Block = (bh, 128 q-rows), 4 waves x 32 q-rows (q = lane&31, hi8 = lane>>5).
// lK: [64 keys][128 bf16 hi|lo] XOR-swizzled (byte ^ ((row&7)<<4)) via linear
//     global_load_lds dest + inverse-swizzled global src; double-buffered.
// Scores: sc = mfma(Kfrag, Qfrag): D[key=(reg&3)+8*(reg>>2)+4*hi8][q=lane&31]
//   -> lane holds 16 scores of ITS q-row. In-lane max/sum + one shfl_xor(32).
// P->frag: cvt_pk pairs + permlane32_swap (word j of frag kc = keys kc*16+hi8*8+2j).
// PV: av = mfma(Vt-frag, Pfrag): D[d-local][q=lane&31] -> lane-local ctx + denom.
// ---------------------------------------------------------------------------
#define KVB 64
#define NKTILES (SEQ/KVB)   // 32

__device__ __forceinline__ void stage_k(const uint16_t* __restrict__ Kb, int kt,
                                        char* dst, int t, int wid){
  const char* gk = (const char*)(Kb + (size_t)kt*KVB*128);
#pragma unroll
  for (int i = 0; i < 4; ++i){
    int tl = i*256 + t;
    int row = tl >> 4;              // 256B-row index of this thread's 16B slot
    int o   = tl*16;
    __builtin_amdgcn_global_load_lds((gas_t)(gk + (o ^ ((row&7)<<4))),
                                     (las_t)(dst + (i*256 + wid*64)*16),
                                     16, 0, 0);
  }
}

#define MFMA32(A,B,C) __builtin_amdgcn_mfma_f32_32x32x16_bf16(A, B, C, 0, 0, 0)

__global__ __launch_bounds__(256)
void attn_fused(const uint16_t* __restrict__ Qs, const uint16_t* __restrict__ Ks,
                const uint16_t* __restrict__ Vt, float* __restrict__ ctx)
{
  __shared__ __align__(16) char lK[2][KVB*256];   // 2 x 16 KB, swizzled
  int t = threadIdx.x, lane = t & 63, wid = t >> 6;
  int l31 = lane & 31, hi8 = lane >> 5;

  // XCD-bijective swizzle: 1024 blocks = 8 XCD x 128
  int orig = blockIdx.x;
  int wg = (orig & 7) * 128 + (orig >> 3);
  int bh = wg >> 4, qt = wg & 15;

  const uint16_t* Qb = Qs + (size_t)bh*SEQ*128;
  const uint16_t* Kb = Ks + (size_t)bh*SEQ*128;
  const uint16_t* Vb = Vt + (size_t)bh*HDIM*SEQ;
  int qg = qt*128 + wid*32 + l31;        // this lane's q-row

  // Q fragments (hi/lo, 4 d-chunks of 16): B-operand row = lane&31 = q.
  short8 qfh[4], qfl[4];
#pragma unroll
  for (int c = 0; c < 4; ++c){
    qfh[c] = *(const short8*)&Qb[(size_t)qg*128 + c*16 + hi8*8];
    qfl[c] = *(const short8*)&Qb[(size_t)qg*128 + 64 + c*16 + hi8*8];
  }

  f32x16 av0 = {}, av1 = {};            // ctx accum: d 0-31, 32-63 (cols = q)
  float m = -1e30f, lh = 0.f;           // log2-domain running max; half-local denom

  stage_k(Kb, 0, lK[0], t, wid);
  __syncthreads();
  int cur = 0;

  for (int kt = 0; kt < NKTILES; ++kt){
    if (kt + 1 < NKTILES) stage_k(Kb, kt + 1, lK[cur ^ 1], t, wid);
    const char* kb = lK[cur];
#pragma unroll
    for (int st = 0; st < 2; ++st){
      // V fragments (global; L1/L2-resident): A-row = d-local = lane&31
      const uint16_t* vb = Vb + (size_t)l31*SEQ + kt*KVB + st*32 + hi8*8;
      short8 vf00 = *(const short8*)(vb);                  // d 0-31,  keys 0-15
      short8 vf01 = *(const short8*)(vb + 16);             // d 0-31,  keys 16-31
      short8 vf10 = *(const short8*)(vb + (size_t)32*SEQ); // d 32-63, keys 0-15
      short8 vf11 = *(const short8*)(vb + (size_t)32*SEQ + 16);

      // K fragments from swizzled LDS; QK^T swapped: sc = K x Q
      int row = st*32 + l31;
      const char* kr = kb + row*256;
      int rx = (row & 7) << 4;
      f32x16 sc = {};
      __builtin_amdgcn_s_setprio(1);
#pragma unroll
      for (int c = 0; c < 4; ++c){
        short8 kfh = *(const short8*)(kr + ((c*32 + hi8*16) ^ rx));
        short8 kfl = *(const short8*)(kr + ((128 + c*32 + hi8*16) ^ rx));
        sc = MFMA32(kfh, qfh[c], sc);   // qh*kh
        sc = MFMA32(kfh, qfl[c], sc);   // ql*kh
        sc = MFMA32(kfl, qfh[c], sc);   // qh*kl
      }
      __builtin_amdgcn_s_setprio(0);

      // ---- lane-local online softmax (log2 domain) ----
      float x01 = fmaxf(sc[0], sc[1]),   x23 = fmaxf(sc[2], sc[3]);
      float x45 = fmaxf(sc[4], sc[5]),   x67 = fmaxf(sc[6], sc[7]);
      float x89 = fmaxf(sc[8], sc[9]),   xab = fmaxf(sc[10], sc[11]);
      float xcd = fmaxf(sc[12], sc[13]), xef = fmaxf(sc[14], sc[15]);
      float pm = fmaxf(fmaxf(fmaxf(x01, x23), fmaxf(x45, x67)),
                       fmaxf(fmaxf(x89, xab), fmaxf(xcd, xef)));
      pm = fmaxf(pm, __shfl_xor(pm, 32));
      if (__any(pm - m > 8.0f)){        // T13 defer-max
        float mn = fmaxf(m, pm);
        float s = __builtin_amdgcn_exp2f(m - mn);
        lh *= s;
#pragma unroll
        for (int i = 0; i < 16; ++i){ av0[i] *= s; av1[i] *= s; }
        m = mn;
      }
      float p[16];
#pragma unroll
      for (int i = 0; i < 16; ++i) p[i] = __builtin_amdgcn_exp2f(sc[i] - m);
      lh += ((p[0]+p[1])+(p[2]+p[3])) + ((p[4]+p[5])+(p[6]+p[7]))
          + ((p[8]+p[9])+(p[10]+p[11])) + ((p[12]+p[13])+(p[14]+p[15]));

      // ---- P -> A-frag in-register (cvt_pk + permlane32_swap) ----
      uint32_t a0,a1,a2,a3,b0,b1,b2,b3;
      asm("v_cvt_pk_bf16_f32 %0, %1, %2" : "=v"(a0) : "v"(p[0]),  "v"(p[1]));
      asm("v_cvt_pk_bf16_f32 %0, %1, %2" : "=v"(a1) : "v"(p[2]),  "v"(p[3]));
      asm("v_cvt_pk_bf16_f32 %0, %1, %2" : "=v"(a2) : "v"(p[4]),  "v"(p[5]));
      asm("v_cvt_pk_bf16_f32 %0, %1, %2" : "=v"(a3) : "v"(p[6]),  "v"(p[7]));
      asm("v_cvt_pk_bf16_f32 %0, %1, %2" : "=v"(b0) : "v"(p[8]),  "v"(p[9]));
      asm("v_cvt_pk_bf16_f32 %0, %1, %2" : "=v"(b1) : "v"(p[10]), "v"(p[11]));
      asm("v_cvt_pk_bf16_f32 %0, %1, %2" : "=v"(b2) : "v"(p[12]), "v"(p[13]));
      asm("v_cvt_pk_bf16_f32 %0, %1, %2" : "=v"(b3) : "v"(p[14]), "v"(p[15]));
      asm volatile("v_permlane32_swap_b32 %0, %1" : "+v"(a0), "+v"(a2));
      asm volatile("v_permlane32_swap_b32 %0, %1" : "+v"(a1), "+v"(a3));
      asm volatile("v_permlane32_swap_b32 %0, %1" : "+v"(b0), "+v"(b2));
      asm volatile("v_permlane32_swap_b32 %0, %1" : "+v"(b1), "+v"(b3));
      u32x4 w0; w0.x=a0; w0.y=a1; w0.z=a2; w0.w=a3;
      u32x4 w1; w1.x=b0; w1.y=b1; w1.z=b2; w1.w=b3;
      short8 pf0 = __builtin_bit_cast(short8, w0);   // keys 0-15 frag
      short8 pf1 = __builtin_bit_cast(short8, w1);   // keys 16-31 frag

      // ---- PV swapped: av = Vt x P ----
      __builtin_amdgcn_s_setprio(1);
      av0 = MFMA32(vf00, pf0, av0);
      av0 = MFMA32(vf01, pf1, av0);
      av1 = MFMA32(vf10, pf0, av1);
      av1 = MFMA32(vf11, pf1, av1);
      __builtin_amdgcn_s_setprio(0);
    }
    __syncthreads();   // lK[cur] consumers done; staged tile landed
    cur ^= 1;
  }

  float lt = lh + __shfl_xor(lh, 32);
  float linv = 1.0f / lt;
  int b = bh >> 4, h = bh & 15;
  float* orow = ctx + ((size_t)b*SEQ + qg)*HID + h*64;
#pragma unroll
  for (int g = 0; g < 4; ++g){
    f32x4 o0, o1;
#pragma unroll
    for (int i = 0; i < 4; ++i){ o0[i] = av0[g*4+i]*linv; o1[i] = av1[g*4+i]*linv; }
    *(f32x4*)(orow + g*8 + hi8*4)      = o0;   // d = g*8 + hi8*4 + i
    *(f32x4*)(orow + 32 + g*8 + hi8*4) = o1;   // d = 32 + ...
  }
}

// ---------------------------------------------------------------------------
extern "C" void kernel_launch(void* const* d_in, const int* in_sizes, int n_in,
                              void* d_out, int out_size, void* d_ws, size_t ws_size,
                              hipStream_t stream)
{
  const float* x  = (const float*)d_in[0];
  const float* Wq = (const float*)d_in[1];
  const float* Wo = (const float*)d_in[2];
  float* out = (float*)d_out;
  char* ws = (char*)d_ws;

  uint16_t* XS = (uint16_t*)(ws);                 // [8192][2048] x split     33.55 MB
  uint16_t* WQ = (uint16_t*)(ws + 33554432);      // [3072][2048] Wqkv split  12.58 MB
  uint16_t* QS = (uint16_t*)(ws + 46137344);      // [bh][s][128] q hi|lo     33.55 MB
  uint16_t* KS = (uint16_t*)(ws + 79691776);      // [bh][s][128] k hi|lo     33.55 MB
  uint16_t* VT = (uint16_t*)(ws + 113246208);     // [bh][d][s]   v bf16      16.78 MB
  float*    CX = (float*)(ws);                    // ctx fp32 (reuses XS)
  uint16_t* CS = (uint16_t*)(ws + 46137344);      // ctx split (reuses QS)
  uint16_t* WS = (uint16_t*)(ws + 33554432);      // Wout split (reuses WQ)

  // q-scale = att_scale * log2(e)  (exp2-domain softmax)
  const float qs = 0.125f * 1.4426950408889634f;

  split_hilo<<<(MROWS*HID)/256, 256, 0, stream>>>(x, XS, MROWS*HID, 0, 1.0f);
  split_hilo<<<(3*HID*HID)/256, 256, 0, stream>>>(Wq, WQ, 3*HID*HID, HID, qs);

  dim3 g1(MROWS/128, (3*HID)/128);
  gemm_split<1><<<g1, 256, 0, stream>>>(XS, WQ, nullptr, QS, KS, VT, MROWS, 3*HID);

  attn_fused<<<dim3(1024), 256, 0, stream>>>(QS, KS, VT, CX);

  split_hilo<<<(MROWS*HID)/256, 256, 0, stream>>>(CX, CS, MROWS*HID, 0, 1.0f);
  split_hilo<<<(HID*HID)/256, 256, 0, stream>>>(Wo, WS, HID*HID, 0, 1.0f);

  dim3 g3(MROWS/128, HID/128);
  gemm_split<0><<<g3, 256, 0, stream>>>(CS, WS, out, nullptr, nullptr, nullptr, MROWS, HID);
}